// Round 1
// baseline (195.477 us; speedup 1.0000x reference)
//
#include <hip/hip_runtime.h>
#include <cstddef>
#include <cstdint>

#define SEQ 2048
#define DM 1024
#define NH 16
#define HD 64

typedef _Float16 f16;
typedef __attribute__((ext_vector_type(8))) _Float16 f16x8;
typedef __attribute__((ext_vector_type(4))) _Float16 f16x4;
typedef __attribute__((ext_vector_type(2))) _Float16 f16x2;
typedef __attribute__((ext_vector_type(4))) float f32x4;

// one launch: cast x (1M float4) + 4 weights (256K float4 each) into the
// contiguous 16 MB f16 region [xb | Wq | Wk | Wv | Wo]
__global__ __launch_bounds__(256) void cast_all(const float* __restrict__ x,
                                                const float* __restrict__ Wq,
                                                const float* __restrict__ Wk,
                                                const float* __restrict__ Wv,
                                                const float* __restrict__ Wo,
                                                f16* __restrict__ dst) {
  const int i = blockIdx.x * 256 + threadIdx.x;  // float4 index, 2M total
  const float* src;
  int off;
  if (i < 1048576) {
    src = x; off = i;
  } else {
    const int j = i - 1048576;
    const int wsel = j >> 18;
    src = (wsel == 0) ? Wq : (wsel == 1) ? Wk : (wsel == 2) ? Wv : Wo;
    off = j & 262143;
  }
  const float4 v = ((const float4*)src)[off];
  f16x4 o = {(f16)v.x, (f16)v.y, (f16)v.z, (f16)v.w};
  ((f16x4*)dst)[i] = o;
}

__device__ __forceinline__ void gload16(const void* g, void* lds) {
  __builtin_amdgcn_global_load_lds((const __attribute__((address_space(1))) void*)g,
                                   (__attribute__((address_space(3))) void*)lds,
                                   16, 0, 0);
}

// ---------------------------------------------------------------------------
// f16 GEMM mainloop (m97 structure).
// ---------------------------------------------------------------------------
__device__ __forceinline__ void gemm_tile(const f16* __restrict__ A,
                                          const f16* __restrict__ B,
                                          f16* As, f16* Bs,
                                          int K, f32x4 acc[4][4]) {
  const int t = threadIdx.x;
  const int lane = t & 63;
  const int w = t >> 6;
  const int wm = (w & 1) << 6, wn = (w >> 1) << 6;
  const int srow = lane >> 2, scol = lane & 3;
  const int fr = lane & 15, q = lane >> 4;
  for (int k0 = 0; k0 < K; k0 += 32) {
    __syncthreads();
#pragma unroll
    for (int c = 0; c < 2; ++c) {
      const int chunk = (w << 1) + c;
      const int row = (chunk << 4) + srow;
      gload16(A + (size_t)row * K + k0 + (scol << 3), As + (chunk << 9));
      gload16(B + (size_t)row * K + k0 + (scol << 3), Bs + (chunk << 9));
    }
    __syncthreads();
    f16x8 af[4], bfr[4];
#pragma unroll
    for (int i = 0; i < 4; ++i)
      af[i] = *(const f16x8*)(As + (wm + (i << 4) + fr) * 32 + (q << 3));
#pragma unroll
    for (int j = 0; j < 4; ++j)
      bfr[j] = *(const f16x8*)(Bs + (wn + (j << 4) + fr) * 32 + (q << 3));
#pragma unroll
    for (int i = 0; i < 4; ++i)
#pragma unroll
      for (int j = 0; j < 4; ++j)
        acc[i][j] = __builtin_amdgcn_mfma_f32_16x16x32_f16(af[i], bfr[j],
                                                           acc[i][j], 0, 0, 0);
  }
}

// Fused QKV projection. Q pre-scaled by log2(e)/sqrt(d_model).
// V stored in gload_lds-linear frag layout; per 64-key tile kt (4096 elems):
//   slot(dt,kcp,quad,fr) = dt*128 + kcp*64 + quad*16 + fr   (16 B per slot)
//   slot holds V[d=dt*16+fr][s = kt*64 + (2*kcp+half)*16 + quad*4 + e],
//   half = (elem>>2)&1, e = elem&3.
// This is byte-identical to the attn LDS image, so staging is a linear copy
// and ds_read_b128 yields two 16x16x16 A-fragments per read.
#define QSCALE 0.04508422003f /* 1.4426950409/32 */
__global__ __launch_bounds__(256) void gemm_qkv(
    const f16* __restrict__ xb, const f16* __restrict__ Wqb,
    const f16* __restrict__ Wkb, const f16* __restrict__ Wvb,
    f16* __restrict__ Qb, f16* __restrict__ Kb, f16* __restrict__ Vtg) {
  __shared__ f16 smem[16384];
  f16* As = smem;
  f16* Bs = smem + 4096;
  const int which = blockIdx.x >> 3;
  const int bn = (blockIdx.x & 7) << 7;
  const int bm = blockIdx.y << 7;
  const f16* B = (which == 0) ? Wqb : (which == 1) ? Wkb : Wvb;
  f32x4 acc[4][4] = {};
  gemm_tile(xb + (size_t)bm * DM, B + (size_t)bn * DM, As, Bs, DM, acc);
  const int lane = threadIdx.x & 63, w = threadIdx.x >> 6;
  const int wm = (w & 1) << 6, wn = (w >> 1) << 6;
  const int col = lane & 15, q = lane >> 4;
  if (which < 2) {
    f16* C = (which == 0) ? Qb : Kb;
    const float sc = (which == 0) ? QSCALE : 1.0f;
#pragma unroll
    for (int i = 0; i < 4; ++i) {
      const int m = bm + wm + (i << 4) + (q << 2);
#pragma unroll
      for (int j = 0; j < 4; ++j) {
        const int n = bn + wn + (j << 4) + col;
#pragma unroll
        for (int r = 0; r < 4; ++r)
          C[(size_t)(m + r) * DM + n] = (f16)(acc[i][j][r] * sc);
      }
    }
  } else {
    // LDS transpose T[nl][m] (swizzled chunks), then frag-layout global stores.
    __syncthreads();
#pragma unroll
    for (int i = 0; i < 4; ++i) {
      const int m0 = wm + (i << 4) + (q << 2);
      const int cm = m0 >> 3, sub = (m0 >> 2) & 1;
#pragma unroll
      for (int j = 0; j < 4; ++j) {
        const int nl = wn + (j << 4) + col;
        f16x4 o = {(f16)acc[i][j][0], (f16)acc[i][j][1],
                   (f16)acc[i][j][2], (f16)acc[i][j][3]};
        *(f16x4*)(smem + nl * 128 +
                  ((cm ^ (nl & 15) ^ ((nl >> 4) & 3)) << 3) + (sub << 2)) = o;
      }
    }
    __syncthreads();
    const int b = bm >> 11, sb = bm & 2047;
    const int d = threadIdx.x & 63;
#pragma unroll
    for (int step = 0; step < 16; ++step) {
      const int idx = (threadIdx.x >> 6) + (step << 2);  // 0..63
      const int hh = idx >> 5, s4 = idx & 31;
      const int nl = (hh << 6) + d;
      const int cm = s4 >> 1, sub = s4 & 1;
      const f16x4 v = *(const f16x4*)(smem + nl * 128 +
                                      ((cm ^ (nl & 15) ^ ((nl >> 4) & 3)) << 3) +
                                      (sub << 2));
      const int bh = (b << 4) + (bn >> 6) + hh;
      const int sg = sb + (s4 << 2);
      // new gload_lds-linear frag layout (see header comment):
      //   kt = sg>>6; dt = d>>4; kcp = (s4>>3)&1; quad = s4&3; fr = d&15;
      //   half = (s4>>2)&1; e packed in the f16x4 store.
      const size_t flat = ((size_t)bh << 17) + ((size_t)(sg >> 6) << 12) +
                          ((size_t)(d >> 4) << 10) + (((size_t)(s4 >> 3) & 1) << 9) +
                          (((size_t)s4 & 3) << 7) + (((size_t)d & 15) << 3) +
                          (((size_t)(s4 >> 2) & 1) << 2);
      *(f16x4*)(Vtg + flat) = v;
    }
  }
}

__global__ __launch_bounds__(256) void gemm_out(const f16* __restrict__ Ab,
                                                const f16* __restrict__ Wob,
                                                float* __restrict__ out) {
  __shared__ f16 As[128 * 32];
  __shared__ f16 Bs[128 * 32];
  const int bn = blockIdx.x << 7, bm = blockIdx.y << 7;
  f32x4 acc[4][4] = {};
  gemm_tile(Ab + (size_t)bm * DM, Wob + (size_t)bn * DM, As, Bs, DM, acc);
  const int lane = threadIdx.x & 63, w = threadIdx.x >> 6;
  const int wm = (w & 1) << 6, wn = (w >> 1) << 6;
  const int col = lane & 15, q = lane >> 4;
#pragma unroll
  for (int i = 0; i < 4; ++i) {
    const int m = bm + wm + (i << 4) + (q << 2);
#pragma unroll
    for (int j = 0; j < 4; ++j) {
      const int n = bn + wn + (j << 4) + col;
#pragma unroll
      for (int r = 0; r < 4; ++r)
        out[(size_t)(m + r) * DM + n] = acc[i][j][r];
    }
  }
}

// ---------------------------------------------------------------------------
// MFMA flash attention R10: K AND V staged via global_load_lds, both
// double-buffered in LDS (4 x 8 KB). Per body per lane: 4 VMEM instructions
// (was 18), zero staging VGPRs, V read once per block (was once per wave).
//  - K source pre-swizzled per lane so the linear gload_lds copy reproduces
//    the cwr-swizzled image the crd ds_reads expect (inverse of cwr).
//  - V source is a linear copy: Vtg layout == LDS image (see gemm_qkv).
//  - MFMA dep chains: QK hf->qt->mt (same z reused at distance 8),
//    PV kc->dt->qt (same acc reused at distance 8) -> throughput-bound issue.
// ---------------------------------------------------------------------------
__global__ __launch_bounds__(256, 2) void attn_mfma(const f16* __restrict__ Qb,
                                                    const f16* __restrict__ Kb,
                                                    const f16* __restrict__ Vtg,
                                                    f16* __restrict__ Ctx) {
  __shared__ f16 smem[16384];  // 32 KB: K0 | K1 | V0 | V1 (8 KB each)
  const int t = threadIdx.x, lane = t & 63, w = t >> 6;
  const int fr = lane & 15, quad = lane >> 4;
  const int i = blockIdx.x;
  const int j = i >> 3;
  const int bh = ((i & 7) << 2) + (j >> 4);
  const int qt16 = j & 15;
  const int b = bh >> 4, h = bh & 15;

  const size_t qrow0 = (size_t)b * SEQ + qt16 * 128 + w * 32;

  // Q^T B-frags, loop-invariant
  f16x8 Qf[2][2];
#pragma unroll
  for (int qt = 0; qt < 2; ++qt)
#pragma unroll
    for (int hf = 0; hf < 2; ++hf)
      Qf[qt][hf] = *(const f16x8*)(Qb + (qrow0 + qt * 16 + fr) * DM + h * HD +
                                   hf * 32 + (quad << 3));

  // K gload_lds: LDS slot s (=lane) must hold global (krow = s>>2,
  // kkc = ((s&3) - (s>>3)) & 3)  — the inverse of cwr(krow,kkc).
  const int krow = lane >> 2;
  const int kkc = ((lane & 3) - (lane >> 3)) & 3;
  const f16* Kg = Kb + ((size_t)b * SEQ + 16 * w + krow) * DM + h * HD + (kkc << 3);
  // V gload_lds: linear copy; wave w stages slots w*128 + c*64 + lane.
  const f16* Vg = Vtg + ((size_t)bh << 17) + (((w << 7) + lane) << 3);

  const int crd = ((fr >> 1) << 3) | ((fr & 1) << 2) | (((fr >> 1) + quad) & 3);

  f16* K0 = smem;
  f16* K1 = smem + 4096;
  f16* V0 = smem + 8192;
  f16* V1 = smem + 12288;

  auto stage = [&](int kt, f16* Kimg, f16* Vimg) {
#pragma unroll
    for (int hf = 0; hf < 2; ++hf)
      gload16(Kg + (size_t)kt * 64 * DM + hf * 32,
              Kimg + (hf << 11) + (w << 9));
#pragma unroll
    for (int c = 0; c < 2; ++c)
      gload16(Vg + kt * 4096 + (c << 9), Vimg + (w << 10) + (c << 9));
  };

  f32x4 acc[2][4] = {};
  float lacc[2] = {0.f, 0.f};

  stage(0, K0, V0);

  auto body = [&](int kt, f16* KR, f16* VR, f16* KW, f16* VW) {
    __syncthreads();  // publishes KR/VR (tile kt); drains last body's prefetch
    if (kt < 31) stage(kt + 1, KW, VW);

    f16x8 Kf[4][2];
#pragma unroll
    for (int mt = 0; mt < 4; ++mt)
#pragma unroll
      for (int hf = 0; hf < 2; ++hf)
        Kf[mt][hf] = *(const f16x8*)(KR + (crd << 3) + (hf << 11) + (mt << 9));
    f16x8 Vf[4][2];
#pragma unroll
    for (int dt = 0; dt < 4; ++dt)
#pragma unroll
      for (int kp = 0; kp < 2; ++kp)
        Vf[dt][kp] = *(const f16x8*)(VR + (((dt << 1) | kp) << 9) +
                                     (quad << 7) + (fr << 3));

    f32x4 z[2][4] = {};
#pragma unroll
    for (int hf = 0; hf < 2; ++hf)
#pragma unroll
      for (int qt = 0; qt < 2; ++qt)
#pragma unroll
        for (int mt = 0; mt < 4; ++mt)
          z[qt][mt] = __builtin_amdgcn_mfma_f32_16x16x32_f16(Kf[mt][hf], Qf[qt][hf],
                                                             z[qt][mt], 0, 0, 0);

    f16x4 pf[2][4];
#pragma unroll
    for (int qt = 0; qt < 2; ++qt)
#pragma unroll
      for (int mt = 0; mt < 4; ++mt) {
        const float p0 = __builtin_amdgcn_exp2f(z[qt][mt][0]);
        const float p1 = __builtin_amdgcn_exp2f(z[qt][mt][1]);
        const float p2 = __builtin_amdgcn_exp2f(z[qt][mt][2]);
        const float p3 = __builtin_amdgcn_exp2f(z[qt][mt][3]);
        lacc[qt] += (p0 + p1) + (p2 + p3);
        const f16x2 lo = __builtin_bit_cast(f16x2, __builtin_amdgcn_cvt_pkrtz(p0, p1));
        const f16x2 hi = __builtin_bit_cast(f16x2, __builtin_amdgcn_cvt_pkrtz(p2, p3));
        f16x4 pv; pv.x = lo.x; pv.y = lo.y; pv.z = hi.x; pv.w = hi.y;
        pf[qt][mt] = pv;
      }

#pragma unroll
    for (int kc = 0; kc < 4; ++kc)
#pragma unroll
      for (int dt = 0; dt < 4; ++dt) {
        const f16x8 v8 = Vf[dt][kc >> 1];
        const f16x4 vh = (kc & 1) ? __builtin_shufflevector(v8, v8, 4, 5, 6, 7)
                                  : __builtin_shufflevector(v8, v8, 0, 1, 2, 3);
#pragma unroll
        for (int qt = 0; qt < 2; ++qt)
          acc[qt][dt] = __builtin_amdgcn_mfma_f32_16x16x16f16(vh, pf[qt][kc],
                                                              acc[qt][dt], 0, 0, 0);
      }
  };

  for (int kt = 0; kt < 32; kt += 2) {
    body(kt, K0, V0, K1, V1);
    body(kt + 1, K1, V1, K0, V0);
  }

  // l reduction over quads (lanes fr, fr+16, fr+32, fr+48 share a q-col)
  float inv[2];
#pragma unroll
  for (int qt = 0; qt < 2; ++qt) {
    float l = lacc[qt];
    l += __shfl_xor(l, 16);
    l += __shfl_xor(l, 32);
    inv[qt] = __builtin_amdgcn_rcpf(l);
  }

  __syncthreads();  // done with K/V images before epilogue reuse
  f16* T = smem + (w << 11);  // wave-private [32 q][64 d]
#pragma unroll
  for (int qt = 0; qt < 2; ++qt)
#pragma unroll
    for (int dt = 0; dt < 4; ++dt) {
      f16x4 o = {(f16)(acc[qt][dt][0] * inv[qt]), (f16)(acc[qt][dt][1] * inv[qt]),
                 (f16)(acc[qt][dt][2] * inv[qt]), (f16)(acc[qt][dt][3] * inv[qt])};
      *(f16x4*)(T + (qt * 16 + fr) * 64 + dt * 16 + (quad << 2)) = o;
    }
#pragma unroll
  for (int p = 0; p < 4; ++p) {
    const int ql = p * 8 + (lane >> 3);
    const f16x8 v = *(const f16x8*)(T + ql * 64 + ((lane & 7) << 3));
    *(f16x8*)(Ctx + (qrow0 + ql) * DM + h * HD + ((lane & 7) << 3)) = v;
  }
}

extern "C" void kernel_launch(void* const* d_in, const int* in_sizes, int n_in,
                              void* d_out, int out_size, void* d_ws, size_t ws_size,
                              hipStream_t stream) {
  const float* x  = (const float*)d_in[0];
  const float* Wq = (const float*)d_in[1];
  const float* Wk = (const float*)d_in[2];
  const float* Wv = (const float*)d_in[3];
  const float* Wo = (const float*)d_in[4];

  char* ws = (char*)d_ws;
  f16* xb  = (f16*)(ws);                 // 8 MB; Wb contiguous after it
  f16* Wb  = (f16*)(ws + (8u << 20));    // 4 x 2 MB: Wq,Wk,Wv,Wo
  f16* Wqb = Wb;
  f16* Wkb = Wb + 1048576;
  f16* Wvb = Wb + 2097152;
  f16* Wob = Wb + 3145728;
  f16* Qb  = (f16*)(ws + (16u << 20));   // 8 MB (pre-scaled by log2e/32)
  f16* Kb  = (f16*)(ws + (24u << 20));
  f16* Vtg = (f16*)(ws + (32u << 20));   // frag-layout V, 8 MB
  f16* Ctx = (f16*)(ws + (40u << 20));   // -> 48 MB total

  cast_all<<<8192, 256, 0, stream>>>(x, Wq, Wk, Wv, Wo, xb);

  gemm_qkv<<<dim3(24, 32), 256, 0, stream>>>(xb, Wqb, Wkb, Wvb, Qb, Kb, Vtg);
  attn_mfma<<<dim3(2 * NH * (SEQ / 128)), 256, 0, stream>>>(Qb, Kb, Vtg, Ctx);
  gemm_out<<<dim3(8, 32), 256, 0, stream>>>(Ctx, Wob, (float*)d_out);
}

// Round 2
// 182.088 us; speedup vs baseline: 1.0735x; 1.0735x over previous
//
#include <hip/hip_runtime.h>
#include <cstddef>
#include <cstdint>

#define SEQ 2048
#define DM 1024
#define NH 16
#define HD 64

typedef _Float16 f16;
typedef __attribute__((ext_vector_type(8))) _Float16 f16x8;
typedef __attribute__((ext_vector_type(4))) _Float16 f16x4;
typedef __attribute__((ext_vector_type(2))) _Float16 f16x2;
typedef __attribute__((ext_vector_type(4))) float f32x4;

// one launch: cast x (1M float4) + 4 weights (256K float4 each) into the
// contiguous 16 MB f16 region [xb | Wq | Wk | Wv | Wo]
__global__ __launch_bounds__(256) void cast_all(const float* __restrict__ x,
                                                const float* __restrict__ Wq,
                                                const float* __restrict__ Wk,
                                                const float* __restrict__ Wv,
                                                const float* __restrict__ Wo,
                                                f16* __restrict__ dst) {
  const int i = blockIdx.x * 256 + threadIdx.x;  // float4 index, 2M total
  const float* src;
  int off;
  if (i < 1048576) {
    src = x; off = i;
  } else {
    const int j = i - 1048576;
    const int wsel = j >> 18;
    src = (wsel == 0) ? Wq : (wsel == 1) ? Wk : (wsel == 2) ? Wv : Wo;
    off = j & 262143;
  }
  const float4 v = ((const float4*)src)[off];
  f16x4 o = {(f16)v.x, (f16)v.y, (f16)v.z, (f16)v.w};
  ((f16x4*)dst)[i] = o;
}

__device__ __forceinline__ void gload16(const void* g, void* lds) {
  __builtin_amdgcn_global_load_lds((const __attribute__((address_space(1))) void*)g,
                                   (__attribute__((address_space(3))) void*)lds,
                                   16, 0, 0);
}

// ---------------------------------------------------------------------------
// f16 GEMM mainloop, BK=64 (16 K-steps, half the barriers of BK=32).
// LDS tiles are XOR-swizzled (T2, st-16B granule): dest col-group sg holds
// source col-group sg^(row&7). gload_lds writes linearly (wave base + lane*16),
// so the swizzle is applied on the per-lane GLOBAL source address (m173) and
// inverted on the ds_read side. Bank math: frag reads land 64x16B over all 32
// banks at 32B/bank = the b128 minimum -> conflict-free.
// ---------------------------------------------------------------------------
__device__ __forceinline__ void gemm_tile(const f16* __restrict__ A,
                                          const f16* __restrict__ B,
                                          f16* As, f16* Bs,
                                          int K, f32x4 acc[4][4]) {
  const int t = threadIdx.x;
  const int lane = t & 63;
  const int w = t >> 6;
  const int wm = (w & 1) << 6, wn = (w >> 1) << 6;
  const int srow = lane >> 3, sg = lane & 7;
  const int fr = lane & 15, q = lane >> 4;
  const int scol = (sg ^ srow) << 3;  // swizzled source col (f16)
  for (int k0 = 0; k0 < K; k0 += 64) {
    __syncthreads();
#pragma unroll
    for (int c = 0; c < 4; ++c) {
      const int row = (w << 5) + (c << 3) + srow;  // row&7 == srow
      gload16(A + (size_t)row * K + k0 + scol, As + (w << 11) + (c << 9));
      gload16(B + (size_t)row * K + k0 + scol, Bs + (w << 11) + (c << 9));
    }
    __syncthreads();
    f16x8 af[4][2], bf[4][2];
#pragma unroll
    for (int i = 0; i < 4; ++i) {
      const int row = wm + (i << 4) + fr;
#pragma unroll
      for (int kh = 0; kh < 2; ++kh)
        af[i][kh] = *(const f16x8*)(As + row * 64 +
                                    ((((kh << 2) | q) ^ (row & 7)) << 3));
    }
#pragma unroll
    for (int j = 0; j < 4; ++j) {
      const int row = wn + (j << 4) + fr;
#pragma unroll
      for (int kh = 0; kh < 2; ++kh)
        bf[j][kh] = *(const f16x8*)(Bs + row * 64 +
                                    ((((kh << 2) | q) ^ (row & 7)) << 3));
    }
#pragma unroll
    for (int kh = 0; kh < 2; ++kh)
#pragma unroll
      for (int i = 0; i < 4; ++i)
#pragma unroll
        for (int j = 0; j < 4; ++j)
          acc[i][j] = __builtin_amdgcn_mfma_f32_16x16x32_f16(af[i][kh], bf[j][kh],
                                                             acc[i][j], 0, 0, 0);
  }
}

// Fused QKV projection. Q pre-scaled by log2(e)/sqrt(d_model).
// V stored in gload_lds-linear frag layout; per 64-key tile kt (4096 elems):
//   flat = bh*131072 + kt*4096 + kc*1024 + quad*256 + d*4 + e
//   holding V[d][s = kt*64 + kc*16 + quad*4 + e]   (d = head dim 0..63)
// The 4KB tile is a byte-linear LDS image for attn; the epilogue's f16x4
// (4 consecutive s, fixed d) is contiguous -> fully coalesced stores.
#define QSCALE 0.04508422003f /* 1.4426950409/32 */
__global__ __launch_bounds__(256) void gemm_qkv(
    const f16* __restrict__ xb, const f16* __restrict__ Wqb,
    const f16* __restrict__ Wkb, const f16* __restrict__ Wvb,
    f16* __restrict__ Qb, f16* __restrict__ Kb, f16* __restrict__ Vtg) {
  __shared__ f16 smem[16384];
  f16* As = smem;
  f16* Bs = smem + 8192;
  const int which = blockIdx.x >> 3;
  const int bn = (blockIdx.x & 7) << 7;
  const int bm = blockIdx.y << 7;
  const f16* B = (which == 0) ? Wqb : (which == 1) ? Wkb : Wvb;
  f32x4 acc[4][4] = {};
  gemm_tile(xb + (size_t)bm * DM, B + (size_t)bn * DM, As, Bs, DM, acc);
  const int lane = threadIdx.x & 63, w = threadIdx.x >> 6;
  const int wm = (w & 1) << 6, wn = (w >> 1) << 6;
  const int col = lane & 15, q = lane >> 4;
  if (which < 2) {
    f16* C = (which == 0) ? Qb : Kb;
    const float sc = (which == 0) ? QSCALE : 1.0f;
#pragma unroll
    for (int i = 0; i < 4; ++i) {
      const int m = bm + wm + (i << 4) + (q << 2);
#pragma unroll
      for (int j = 0; j < 4; ++j) {
        const int n = bn + wn + (j << 4) + col;
#pragma unroll
        for (int r = 0; r < 4; ++r)
          C[(size_t)(m + r) * DM + n] = (f16)(acc[i][j][r] * sc);
      }
    }
  } else {
    // LDS transpose T[nl][m] (swizzled chunks), then frag-layout global stores.
    __syncthreads();
#pragma unroll
    for (int i = 0; i < 4; ++i) {
      const int m0 = wm + (i << 4) + (q << 2);
      const int cm = m0 >> 3, sub = (m0 >> 2) & 1;
#pragma unroll
      for (int j = 0; j < 4; ++j) {
        const int nl = wn + (j << 4) + col;
        f16x4 o = {(f16)acc[i][j][0], (f16)acc[i][j][1],
                   (f16)acc[i][j][2], (f16)acc[i][j][3]};
        *(f16x4*)(smem + nl * 128 +
                  ((cm ^ (nl & 15) ^ ((nl >> 4) & 3)) << 3) + (sub << 2)) = o;
      }
    }
    __syncthreads();
    const int b = bm >> 11, sb = bm & 2047;
    const int d = threadIdx.x & 63;
#pragma unroll
    for (int step = 0; step < 16; ++step) {
      const int idx = (threadIdx.x >> 6) + (step << 2);  // 0..63
      const int hh = idx >> 5, s4 = idx & 31;
      const int nl = (hh << 6) + d;
      const int cm = s4 >> 1, sub = s4 & 1;
      const f16x4 v = *(const f16x4*)(smem + nl * 128 +
                                      ((cm ^ (nl & 15) ^ ((nl >> 4) & 3)) << 3) +
                                      (sub << 2));
      const int bh = (b << 4) + (bn >> 6) + hh;
      const int sg = sb + (s4 << 2);
      // flat = bh*131072 + kt*4096 + kc*1024 + quad*256 + d*4 (+ e from f16x4)
      const size_t flat = ((size_t)bh << 17) + ((size_t)(sg >> 6) << 12) +
                          (((size_t)(s4 >> 2) & 3) << 10) +
                          (((size_t)s4 & 3) << 8) + ((size_t)d << 2);
      *(f16x4*)(Vtg + flat) = v;
    }
  }
}

// Output projection: 128x64 tiles, BK=64, grid (16,32)=512 blocks (2/CU;
// the old 128x128 grid was 256 blocks = 1 block/CU = 1 wave/SIMD, no
// latency hiding). 4 waves stacked on M (32 rows each), acc[2][4].
__global__ __launch_bounds__(256) void gemm_out(const f16* __restrict__ Ab,
                                                const f16* __restrict__ Wob,
                                                float* __restrict__ out) {
  __shared__ f16 As[128 * 64];
  __shared__ f16 Bs[64 * 64];
  const int bn = blockIdx.x << 6, bm = blockIdx.y << 7;
  const int t = threadIdx.x, lane = t & 63, w = t >> 6;
  const int srow = lane >> 3, sg = lane & 7;
  const int fr = lane & 15, q = lane >> 4;
  const int scol = (sg ^ srow) << 3;
  const f16* A = Ab + (size_t)bm * DM;
  const f16* B = Wob + (size_t)bn * DM;
  const int wm = w << 5;
  f32x4 acc[2][4] = {};
  for (int k0 = 0; k0 < DM; k0 += 64) {
    __syncthreads();
#pragma unroll
    for (int c = 0; c < 4; ++c) {
      const int row = (w << 5) + (c << 3) + srow;
      gload16(A + (size_t)row * DM + k0 + scol, As + (w << 11) + (c << 9));
    }
#pragma unroll
    for (int c = 0; c < 2; ++c) {
      const int row = (w << 4) + (c << 3) + srow;
      gload16(B + (size_t)row * DM + k0 + scol, Bs + (w << 10) + (c << 9));
    }
    __syncthreads();
    f16x8 af[2][2], bf[4][2];
#pragma unroll
    for (int i = 0; i < 2; ++i) {
      const int row = wm + (i << 4) + fr;
#pragma unroll
      for (int kh = 0; kh < 2; ++kh)
        af[i][kh] = *(const f16x8*)(As + row * 64 +
                                    ((((kh << 2) | q) ^ (row & 7)) << 3));
    }
#pragma unroll
    for (int j = 0; j < 4; ++j) {
      const int row = (j << 4) + fr;
#pragma unroll
      for (int kh = 0; kh < 2; ++kh)
        bf[j][kh] = *(const f16x8*)(Bs + row * 64 +
                                    ((((kh << 2) | q) ^ (row & 7)) << 3));
    }
#pragma unroll
    for (int kh = 0; kh < 2; ++kh)
#pragma unroll
      for (int i = 0; i < 2; ++i)
#pragma unroll
        for (int j = 0; j < 4; ++j)
          acc[i][j] = __builtin_amdgcn_mfma_f32_16x16x32_f16(af[i][kh], bf[j][kh],
                                                             acc[i][j], 0, 0, 0);
  }
  const int col = lane & 15;
#pragma unroll
  for (int i = 0; i < 2; ++i) {
    const int m = bm + wm + (i << 4) + (q << 2);
#pragma unroll
    for (int j = 0; j < 4; ++j) {
      const int n = bn + (j << 4) + col;
#pragma unroll
      for (int r = 0; r < 4; ++r)
        out[(size_t)(m + r) * DM + n] = acc[i][j][r];
    }
  }
}

// ---------------------------------------------------------------------------
// MFMA flash attention R11: K and V staged via global_load_lds, both
// double-buffered in LDS (4 x 8 KB). V frags now ds_read_b64 from the
// [kc][quad][d][e] tile image (conflict-free: 64 lanes x 8B = 4 cy = b64 min).
// ---------------------------------------------------------------------------
__global__ __launch_bounds__(256, 2) void attn_mfma(const f16* __restrict__ Qb,
                                                    const f16* __restrict__ Kb,
                                                    const f16* __restrict__ Vtg,
                                                    f16* __restrict__ Ctx) {
  __shared__ f16 smem[16384];  // 32 KB: K0 | K1 | V0 | V1 (8 KB each)
  const int t = threadIdx.x, lane = t & 63, w = t >> 6;
  const int fr = lane & 15, quad = lane >> 4;
  const int i = blockIdx.x;
  const int j = i >> 3;
  const int bh = ((i & 7) << 2) + (j >> 4);
  const int qt16 = j & 15;
  const int b = bh >> 4, h = bh & 15;

  const size_t qrow0 = (size_t)b * SEQ + qt16 * 128 + w * 32;

  // Q^T B-frags, loop-invariant
  f16x8 Qf[2][2];
#pragma unroll
  for (int qt = 0; qt < 2; ++qt)
#pragma unroll
    for (int hf = 0; hf < 2; ++hf)
      Qf[qt][hf] = *(const f16x8*)(Qb + (qrow0 + qt * 16 + fr) * DM + h * HD +
                                   hf * 32 + (quad << 3));

  // K gload_lds: LDS slot s (=lane) must hold global (krow = s>>2,
  // kkc = ((s&3) - (s>>3)) & 3)  — the inverse of cwr(krow,kkc).
  const int krow = lane >> 2;
  const int kkc = ((lane & 3) - (lane >> 3)) & 3;
  const f16* Kg = Kb + ((size_t)b * SEQ + 16 * w + krow) * DM + h * HD + (kkc << 3);
  // V gload_lds: linear copy; wave w stages slots w*128 + c*64 + lane.
  const f16* Vg = Vtg + ((size_t)bh << 17) + (((w << 7) + lane) << 3);

  const int crd = ((fr >> 1) << 3) | ((fr & 1) << 2) | (((fr >> 1) + quad) & 3);

  f16* K0 = smem;
  f16* K1 = smem + 4096;
  f16* V0 = smem + 8192;
  f16* V1 = smem + 12288;

  auto stage = [&](int kt, f16* Kimg, f16* Vimg) {
#pragma unroll
    for (int hf = 0; hf < 2; ++hf)
      gload16(Kg + (size_t)kt * 64 * DM + hf * 32,
              Kimg + (hf << 11) + (w << 9));
#pragma unroll
    for (int c = 0; c < 2; ++c)
      gload16(Vg + kt * 4096 + (c << 9), Vimg + (w << 10) + (c << 9));
  };

  f32x4 acc[2][4] = {};
  float lacc[2] = {0.f, 0.f};

  stage(0, K0, V0);

  auto body = [&](int kt, f16* KR, f16* VR, f16* KW, f16* VW) {
    __syncthreads();  // publishes KR/VR (tile kt); drains last body's prefetch
    if (kt < 31) stage(kt + 1, KW, VW);

    f16x8 Kf[4][2];
#pragma unroll
    for (int mt = 0; mt < 4; ++mt)
#pragma unroll
      for (int hf = 0; hf < 2; ++hf)
        Kf[mt][hf] = *(const f16x8*)(KR + (crd << 3) + (hf << 11) + (mt << 9));
    f16x4 Vf[4][4];
#pragma unroll
    for (int dt = 0; dt < 4; ++dt)
#pragma unroll
      for (int kc = 0; kc < 4; ++kc)
        Vf[dt][kc] = *(const f16x4*)(VR + (kc << 10) + (quad << 8) +
                                     (((dt << 4) | fr) << 2));

    f32x4 z[2][4] = {};
#pragma unroll
    for (int hf = 0; hf < 2; ++hf)
#pragma unroll
      for (int qt = 0; qt < 2; ++qt)
#pragma unroll
        for (int mt = 0; mt < 4; ++mt)
          z[qt][mt] = __builtin_amdgcn_mfma_f32_16x16x32_f16(Kf[mt][hf], Qf[qt][hf],
                                                             z[qt][mt], 0, 0, 0);

    f16x4 pf[2][4];
#pragma unroll
    for (int qt = 0; qt < 2; ++qt)
#pragma unroll
      for (int mt = 0; mt < 4; ++mt) {
        const float p0 = __builtin_amdgcn_exp2f(z[qt][mt][0]);
        const float p1 = __builtin_amdgcn_exp2f(z[qt][mt][1]);
        const float p2 = __builtin_amdgcn_exp2f(z[qt][mt][2]);
        const float p3 = __builtin_amdgcn_exp2f(z[qt][mt][3]);
        lacc[qt] += (p0 + p1) + (p2 + p3);
        const f16x2 lo = __builtin_bit_cast(f16x2, __builtin_amdgcn_cvt_pkrtz(p0, p1));
        const f16x2 hi = __builtin_bit_cast(f16x2, __builtin_amdgcn_cvt_pkrtz(p2, p3));
        f16x4 pv; pv.x = lo.x; pv.y = lo.y; pv.z = hi.x; pv.w = hi.y;
        pf[qt][mt] = pv;
      }

#pragma unroll
    for (int kc = 0; kc < 4; ++kc)
#pragma unroll
      for (int dt = 0; dt < 4; ++dt)
#pragma unroll
        for (int qt = 0; qt < 2; ++qt)
          acc[qt][dt] = __builtin_amdgcn_mfma_f32_16x16x16f16(Vf[dt][kc], pf[qt][kc],
                                                              acc[qt][dt], 0, 0, 0);
  };

  for (int kt = 0; kt < 32; kt += 2) {
    body(kt, K0, V0, K1, V1);
    body(kt + 1, K1, V1, K0, V0);
  }

  // l reduction over quads (lanes fr, fr+16, fr+32, fr+48 share a q-col)
  float inv[2];
#pragma unroll
  for (int qt = 0; qt < 2; ++qt) {
    float l = lacc[qt];
    l += __shfl_xor(l, 16);
    l += __shfl_xor(l, 32);
    inv[qt] = __builtin_amdgcn_rcpf(l);
  }

  __syncthreads();  // done with K/V images before epilogue reuse
  f16* T = smem + (w << 11);  // wave-private [32 q][64 d]
#pragma unroll
  for (int qt = 0; qt < 2; ++qt)
#pragma unroll
    for (int dt = 0; dt < 4; ++dt) {
      f16x4 o = {(f16)(acc[qt][dt][0] * inv[qt]), (f16)(acc[qt][dt][1] * inv[qt]),
                 (f16)(acc[qt][dt][2] * inv[qt]), (f16)(acc[qt][dt][3] * inv[qt])};
      *(f16x4*)(T + (qt * 16 + fr) * 64 + dt * 16 + (quad << 2)) = o;
    }
#pragma unroll
  for (int p = 0; p < 4; ++p) {
    const int ql = p * 8 + (lane >> 3);
    const f16x8 v = *(const f16x8*)(T + ql * 64 + ((lane & 7) << 3));
    *(f16x8*)(Ctx + (qrow0 + ql) * DM + h * HD + ((lane & 7) << 3)) = v;
  }
}

extern "C" void kernel_launch(void* const* d_in, const int* in_sizes, int n_in,
                              void* d_out, int out_size, void* d_ws, size_t ws_size,
                              hipStream_t stream) {
  const float* x  = (const float*)d_in[0];
  const float* Wq = (const float*)d_in[1];
  const float* Wk = (const float*)d_in[2];
  const float* Wv = (const float*)d_in[3];
  const float* Wo = (const float*)d_in[4];

  char* ws = (char*)d_ws;
  f16* xb  = (f16*)(ws);                 // 8 MB; Wb contiguous after it
  f16* Wb  = (f16*)(ws + (8u << 20));    // 4 x 2 MB: Wq,Wk,Wv,Wo
  f16* Wqb = Wb;
  f16* Wkb = Wb + 1048576;
  f16* Wvb = Wb + 2097152;
  f16* Wob = Wb + 3145728;
  f16* Qb  = (f16*)(ws + (16u << 20));   // 8 MB (pre-scaled by log2e/32)
  f16* Kb  = (f16*)(ws + (24u << 20));
  f16* Vtg = (f16*)(ws + (32u << 20));   // frag-layout V, 8 MB
  f16* Ctx = (f16*)(ws + (40u << 20));   // -> 48 MB total

  cast_all<<<8192, 256, 0, stream>>>(x, Wq, Wk, Wv, Wo, xb);

  gemm_qkv<<<dim3(24, 32), 256, 0, stream>>>(xb, Wqb, Wkb, Wvb, Qb, Kb, Vtg);
  attn_mfma<<<dim3(2 * NH * (SEQ / 128)), 256, 0, stream>>>(Qb, Kb, Vtg, Ctx);
  gemm_out<<<dim3(16, 32), 256, 0, stream>>>(Ctx, Wob, (float*)d_out);
}